// Round 5
// baseline (132.283 us; speedup 1.0000x reference)
//
#include <hip/hip_runtime.h>

#define HH 128
#define WW 128

typedef __bf16 bf16x8 __attribute__((ext_vector_type(8)));
typedef float f32x4 __attribute__((ext_vector_type(4)));

static __device__ __forceinline__ unsigned short f2bf(float f) {
  unsigned int u = __float_as_uint(f);
  u = (u + 0x7FFFu + ((u >> 16) & 1u)) >> 16;  // RNE
  return (unsigned short)u;
}

// ---------------------------------------------------------------------------
// Prep 1: pack conv_w [co][ci][tap] into MFMA A-fragment order (bf16):
//   wfrag[f = h*9+tap][cotile][lane][i] = conv_w[cotile*16 + lane%16]
//                                               [h*32 + (lane/16)*8 + i][tap]
// ---------------------------------------------------------------------------
__global__ __launch_bounds__(256) void prep_wfrag(const float* __restrict__ conv_w,
                                                  unsigned short* __restrict__ wfrag) {
  int tid = blockIdx.x * 256 + threadIdx.x;
  if (tid >= 18 * 2048) return;
  int i    = tid & 7;
  int lane = (tid >> 3) & 63;
  int cot  = (tid >> 9) & 3;
  int f    = tid >> 11;           // 0..17
  int h    = f / 9;               // ci half
  int tap  = f - h * 9;
  int co   = cot * 16 + (lane & 15);
  int ci   = h * 32 + (lane >> 4) * 8 + i;
  wfrag[tid] = f2bf(conv_w[(co * 64 + ci) * 9 + tap]);
}

// ---------------------------------------------------------------------------
// Prep 2: grouped conv of spatially-constant input -> 9-case boundary table
//   ext[b][co][cy][cx]  (includes conv_b + extra_b)
// ---------------------------------------------------------------------------
__global__ __launch_bounds__(256) void prep_ext(const float* __restrict__ extra_in,
                                                const float* __restrict__ extra_w,
                                                const float* __restrict__ conv_b,
                                                const float* __restrict__ extra_b,
                                                float* __restrict__ ext) {
  int t = blockIdx.x * 256 + threadIdx.x;
  if (t >= 32 * 64) return;
  int b = t >> 6, co = t & 63;
  float base = conv_b[co] + extra_b[co];
  float acc[3][3];
#pragma unroll
  for (int i = 0; i < 3; ++i)
#pragma unroll
    for (int j = 0; j < 3; ++j) acc[i][j] = 0.f;

#pragma unroll
  for (int f = 0; f < 3; ++f) {
    float e = extra_in[b * 192 + co * 3 + f];
    const float* w = extra_w + (co * 3 + f) * 9;
    float rs[3][3];
#pragma unroll
    for (int ky = 0; ky < 3; ++ky) {
      float w0 = w[ky * 3 + 0], w1 = w[ky * 3 + 1], w2 = w[ky * 3 + 2];
      rs[ky][0] = w1 + w2;
      rs[ky][1] = w0 + w1 + w2;
      rs[ky][2] = w0 + w1;
    }
#pragma unroll
    for (int cx = 0; cx < 3; ++cx) {
      acc[0][cx] += e * (rs[1][cx] + rs[2][cx]);
      acc[1][cx] += e * (rs[0][cx] + rs[1][cx] + rs[2][cx]);
      acc[2][cx] += e * (rs[0][cx] + rs[1][cx]);
    }
  }
#pragma unroll
  for (int cy = 0; cy < 3; ++cy)
#pragma unroll
    for (int cx = 0; cx < 3; ++cx)
      ext[t * 9 + cy * 3 + cx] = base + acc[cy][cx];
}

// ---------------------------------------------------------------------------
// Main: implicit-GEMM conv via mfma_f32_16x16x32_bf16.
// Block = (batch, 8 rows x 64 cols), 512 thr = 8 waves, wave = 1 output row.
// Halo 10x66, staged per ci-half into LDS [10 r][68 c][32 ci] bf16 (43.5 KB).
// Interior columns staged with float2 (x pairs, 8B-aligned); border columns
// (c=0, c=65) with a small scalar path. Compute phases contain ONLY af loads
// in the vmcnt queue (no staging) so MFMA waits never drain staging loads.
// Swizzle: byte ^= ((c ^ (c>>2)) & 3) << 4  (2-way lane aliasing = free).
// ---------------------------------------------------------------------------
__global__ __launch_bounds__(512, 3) void conv_mfma(const float* __restrict__ x,
                                                    const unsigned short* __restrict__ wfrag,
                                                    const float* __restrict__ ext,
                                                    float* __restrict__ out) {
  const int b  = blockIdx.z;
  const int y0 = blockIdx.y * 8;
  const int x0 = blockIdx.x * 64;
  const int tid  = threadIdx.x;
  const int lane = tid & 63;
  const int wv   = tid >> 6;  // wave id = output row offset (0..7)

  __shared__ __align__(16) unsigned char sbuf[10 * 68 * 64];  // [r][c][32ci] bf16

  const float* xb = x + (size_t)b * 64 * HH * WW;

  f32x4 acc[4][4];
#pragma unroll
  for (int i = 0; i < 4; ++i)
#pragma unroll
    for (int j = 0; j < 4; ++j) acc[i][j] = (f32x4){0.f, 0.f, 0.f, 0.f};

  const int pix = lane & 15;
  const int g   = lane >> 4;

  // ---- stage one ci-half (h) of the 10x66 halo into sbuf ----
  auto stage_half = [&](int h) {
    // interior: c = 1+2*cp (cp 0..31), x_in = x0+2*cp (8B-aligned float2)
#pragma unroll
    for (int it = 0; it < 3; ++it) {
      int q = tid + it * 512;
      if (q < 1280) {
        int cp  = q & 31;
        int cig = (q >> 5) & 3;
        int r   = q >> 7;          // 0..9
        int c   = 1 + 2 * cp;
        int y_in = y0 - 1 + r;
        int x_in = x0 + 2 * cp;
        unsigned int pkA[4] = {0u, 0u, 0u, 0u};
        unsigned int pkB[4] = {0u, 0u, 0u, 0u};
        if ((unsigned)y_in < 128u) {
          const float* src = xb + (size_t)(h * 32 + cig * 8) * (HH * WW) + y_in * WW + x_in;
#pragma unroll
          for (int j = 0; j < 8; ++j) {
            float2 f = *(const float2*)(src + (size_t)j * (HH * WW));
            pkA[j >> 1] |= ((unsigned int)f2bf(f.x)) << ((j & 1) * 16);
            pkB[j >> 1] |= ((unsigned int)f2bf(f.y)) << ((j & 1) * 16);
          }
        }
        int baseA = (r * 68 + c) * 64 + cig * 16;
        int baseB = (r * 68 + c + 1) * 64 + cig * 16;
        baseA ^= ((c ^ (c >> 2)) & 3) << 4;
        baseB ^= (((c + 1) ^ ((c + 1) >> 2)) & 3) << 4;
        *(uint4*)(sbuf + baseA) = make_uint4(pkA[0], pkA[1], pkA[2], pkA[3]);
        *(uint4*)(sbuf + baseB) = make_uint4(pkB[0], pkB[1], pkB[2], pkB[3]);
      }
    }
    // border: c in {0, 65}
    if (tid < 80) {
      int c   = (tid & 1) ? 65 : 0;
      int cig = (tid >> 1) & 3;
      int r   = tid >> 3;          // 0..9
      int y_in = y0 - 1 + r;
      int x_in = x0 - 1 + c;
      bool inb = ((unsigned)y_in < 128u) & ((unsigned)x_in < 128u);
      unsigned int pk[4] = {0u, 0u, 0u, 0u};
      if (inb) {
        const float* src = xb + (size_t)(h * 32 + cig * 8) * (HH * WW) + y_in * WW + x_in;
#pragma unroll
        for (int j = 0; j < 8; ++j) {
          unsigned short us = f2bf(src[(size_t)j * (HH * WW)]);
          pk[j >> 1] |= ((unsigned int)us) << ((j & 1) * 16);
        }
      }
      int byte = (r * 68 + c) * 64 + cig * 16;
      byte ^= ((c ^ (c >> 2)) & 3) << 4;
      *(uint4*)(sbuf + byte) = make_uint4(pk[0], pk[1], pk[2], pk[3]);
    }
  };

  auto compute_half = [&](int h) {
#pragma unroll
    for (int tap = 0; tap < 9; ++tap) {
      const int ky = tap / 3, kx = tap - ky * 3;
      const unsigned short* wbase = wfrag + (size_t)(h * 9 + tap) * 2048 + lane * 8;
      bf16x8 af[4];
#pragma unroll
      for (int cot = 0; cot < 4; ++cot)
        af[cot] = *(const bf16x8*)(wbase + cot * 512);
      bf16x8 pf[4];
      const int r = wv + ky;
#pragma unroll
      for (int m = 0; m < 4; ++m) {
        int c = m * 16 + pix + kx;
        int byte = (r * 68 + c) * 64 + g * 16;
        byte ^= ((c ^ (c >> 2)) & 3) << 4;
        pf[m] = *(const bf16x8*)(sbuf + byte);
      }
#pragma unroll
      for (int cot = 0; cot < 4; ++cot)
#pragma unroll
        for (int m = 0; m < 4; ++m)
          acc[cot][m] = __builtin_amdgcn_mfma_f32_16x16x32_bf16(af[cot], pf[m],
                                                                acc[cot][m], 0, 0, 0);
    }
  };

  stage_half(0);
  __syncthreads();
  compute_half(0);
  __syncthreads();
  stage_half(1);
  __syncthreads();
  compute_half(1);

  // ---- epilogue: add boundary-case table, coalesced stores ----
  const int y  = y0 + wv;
  const int cy = (y == 0) ? 0 : ((y == HH - 1) ? 2 : 1);
  const float* extb = ext + (size_t)b * 64 * 9;
#pragma unroll
  for (int cot = 0; cot < 4; ++cot) {
#pragma unroll
    for (int m = 0; m < 4; ++m) {
      int xg = x0 + m * 16 + pix;
      int cx = (xg == 0) ? 0 : ((xg == WW - 1) ? 2 : 1);
#pragma unroll
      for (int j = 0; j < 4; ++j) {
        int co = cot * 16 + g * 4 + j;
        float v = acc[cot][m][j] + extb[co * 9 + cy * 3 + cx];
        out[(((size_t)b * 64 + co) * HH + y) * WW + xg] = v;
      }
    }
  }
}

extern "C" void kernel_launch(void* const* d_in, const int* in_sizes, int n_in,
                              void* d_out, int out_size, void* d_ws, size_t ws_size,
                              hipStream_t stream) {
  const float* x        = (const float*)d_in[0];
  const float* extra_in = (const float*)d_in[1];
  const float* conv_w   = (const float*)d_in[2];
  const float* conv_b   = (const float*)d_in[3];
  const float* extra_w  = (const float*)d_in[4];
  const float* extra_b  = (const float*)d_in[5];
  float* out = (float*)d_out;

  unsigned short* wfrag = (unsigned short*)d_ws;              // 73728 B
  float* ext = (float*)((char*)d_ws + 73728);                 // 73728 B

  hipLaunchKernelGGL(prep_wfrag, dim3(144), dim3(256), 0, stream, conv_w, wfrag);
  hipLaunchKernelGGL(prep_ext,   dim3(8),   dim3(256), 0, stream,
                     extra_in, extra_w, conv_b, extra_b, ext);
  hipLaunchKernelGGL(conv_mfma, dim3(2, 16, 32), dim3(512), 0, stream,
                     x, wfrag, ext, out);
}

// Round 6
// 109.333 us; speedup vs baseline: 1.2099x; 1.2099x over previous
//
#include <hip/hip_runtime.h>

#define HH 128
#define WW 128

typedef __bf16 bf16x8 __attribute__((ext_vector_type(8)));
typedef __bf16 bf16x2 __attribute__((ext_vector_type(2)));
typedef float f32x4 __attribute__((ext_vector_type(4)));

static __device__ __forceinline__ unsigned short f2bf(float f) {
  unsigned int u = __float_as_uint(f);
  u = (u + 0x7FFFu + ((u >> 16) & 1u)) >> 16;  // RNE
  return (unsigned short)u;
}

// hardware packed f32->bf16 (RNE), 2 elems -> one u32
static __device__ __forceinline__ unsigned int pack2bf(float lo, float hi) {
  bf16x2 v;
  v[0] = (__bf16)lo;
  v[1] = (__bf16)hi;
  return __builtin_bit_cast(unsigned int, v);
}

// ---------------------------------------------------------------------------
// Prep 1: pack conv_w [co][ci][tap] into MFMA A-fragment order (bf16):
//   wfrag[f = h*9+tap][cotile][lane][i] = conv_w[cotile*16 + lane%16]
//                                               [h*32 + (lane/16)*8 + i][tap]
// ---------------------------------------------------------------------------
__global__ __launch_bounds__(256) void prep_wfrag(const float* __restrict__ conv_w,
                                                  unsigned short* __restrict__ wfrag) {
  int tid = blockIdx.x * 256 + threadIdx.x;
  if (tid >= 18 * 2048) return;
  int i    = tid & 7;
  int lane = (tid >> 3) & 63;
  int cot  = (tid >> 9) & 3;
  int f    = tid >> 11;           // 0..17
  int h    = f / 9;               // ci half
  int tap  = f - h * 9;
  int co   = cot * 16 + (lane & 15);
  int ci   = h * 32 + (lane >> 4) * 8 + i;
  wfrag[tid] = f2bf(conv_w[(co * 64 + ci) * 9 + tap]);
}

// ---------------------------------------------------------------------------
// Prep 2: grouped conv of spatially-constant input -> 9-case boundary table
//   ext[b][co][cy][cx]  (includes conv_b + extra_b)
// ---------------------------------------------------------------------------
__global__ __launch_bounds__(256) void prep_ext(const float* __restrict__ extra_in,
                                                const float* __restrict__ extra_w,
                                                const float* __restrict__ conv_b,
                                                const float* __restrict__ extra_b,
                                                float* __restrict__ ext) {
  int t = blockIdx.x * 256 + threadIdx.x;
  if (t >= 32 * 64) return;
  int b = t >> 6, co = t & 63;
  float base = conv_b[co] + extra_b[co];
  float acc[3][3];
#pragma unroll
  for (int i = 0; i < 3; ++i)
#pragma unroll
    for (int j = 0; j < 3; ++j) acc[i][j] = 0.f;

#pragma unroll
  for (int f = 0; f < 3; ++f) {
    float e = extra_in[b * 192 + co * 3 + f];
    const float* w = extra_w + (co * 3 + f) * 9;
    float rs[3][3];
#pragma unroll
    for (int ky = 0; ky < 3; ++ky) {
      float w0 = w[ky * 3 + 0], w1 = w[ky * 3 + 1], w2 = w[ky * 3 + 2];
      rs[ky][0] = w1 + w2;
      rs[ky][1] = w0 + w1 + w2;
      rs[ky][2] = w0 + w1;
    }
#pragma unroll
    for (int cx = 0; cx < 3; ++cx) {
      acc[0][cx] += e * (rs[1][cx] + rs[2][cx]);
      acc[1][cx] += e * (rs[0][cx] + rs[1][cx] + rs[2][cx]);
      acc[2][cx] += e * (rs[0][cx] + rs[1][cx]);
    }
  }
#pragma unroll
  for (int cy = 0; cy < 3; ++cy)
#pragma unroll
    for (int cx = 0; cx < 3; ++cx)
      ext[t * 9 + cy * 3 + cx] = base + acc[cy][cx];
}

// ---------------------------------------------------------------------------
// Main: implicit-GEMM conv via mfma_f32_16x16x32_bf16 (r3 chassis).
// Block = (batch, 4 rows x 64 cols), 4 waves, wave = 1 output row.
// ci halves staged one at a time into LDS [6 r][68 c][32 ci] bf16 (25.5 KB).
// Staging: float2 interior pairs (guard-free 3x256 items) + scalar border;
// hardware v_cvt_pk bf16 conversion. Strict stage->sync->compute phases.
// Swizzle: byte ^= ((c ^ (c>>2)) & 3) << 4  (2-way lane aliasing = free).
// ---------------------------------------------------------------------------
__global__ __launch_bounds__(256, 3) void conv_mfma(const float* __restrict__ x,
                                                    const unsigned short* __restrict__ wfrag,
                                                    const float* __restrict__ ext,
                                                    float* __restrict__ out) {
  const int b  = blockIdx.z;
  const int y0 = blockIdx.y * 4;
  const int x0 = blockIdx.x * 64;
  const int tid  = threadIdx.x;
  const int lane = tid & 63;
  const int wv   = tid >> 6;  // wave id = output row offset

  __shared__ __align__(16) unsigned char sbuf[6 * 68 * 64];  // [r][c][32ci] bf16

  const float* xb = x + (size_t)b * 64 * HH * WW;

  f32x4 acc[4][4];
#pragma unroll
  for (int i = 0; i < 4; ++i)
#pragma unroll
    for (int j = 0; j < 4; ++j) acc[i][j] = (f32x4){0.f, 0.f, 0.f, 0.f};

  const int pix = lane & 15;
  const int g   = lane >> 4;

  // ---- stage one ci-half (h) of the 6x66 halo into sbuf ----
  auto stage_half = [&](int h) {
    // interior: c pairs (1+2cp, 2+2cp), cp 0..31; 32*4*6 = 768 = 3*256 items
#pragma unroll
    for (int it = 0; it < 3; ++it) {
      int q   = tid + it * 256;
      int cp  = q & 31;
      int cig = (q >> 5) & 3;
      int r   = q >> 7;            // 0..5
      int c   = 1 + 2 * cp;
      int y_in = y0 - 1 + r;
      int x_in = x0 + 2 * cp;      // = x0 - 1 + c, even -> 8B aligned
      unsigned int pkA[4] = {0u, 0u, 0u, 0u};
      unsigned int pkB[4] = {0u, 0u, 0u, 0u};
      if ((unsigned)y_in < 128u) {
        const float* src = xb + (size_t)(h * 32 + cig * 8) * (HH * WW) + y_in * WW + x_in;
        float2 f[8];
#pragma unroll
        for (int j = 0; j < 8; ++j) f[j] = *(const float2*)(src + (size_t)j * (HH * WW));
#pragma unroll
        for (int w = 0; w < 4; ++w) {
          pkA[w] = pack2bf(f[2 * w].x, f[2 * w + 1].x);
          pkB[w] = pack2bf(f[2 * w].y, f[2 * w + 1].y);
        }
      }
      int baseA = (r * 68 + c) * 64 + cig * 16;
      int baseB = (r * 68 + c + 1) * 64 + cig * 16;
      baseA ^= ((c ^ (c >> 2)) & 3) << 4;
      baseB ^= (((c + 1) ^ ((c + 1) >> 2)) & 3) << 4;
      *(uint4*)(sbuf + baseA) = make_uint4(pkA[0], pkA[1], pkA[2], pkA[3]);
      *(uint4*)(sbuf + baseB) = make_uint4(pkB[0], pkB[1], pkB[2], pkB[3]);
    }
    // border: c in {0, 65}; 2*4*6 = 48 items
    if (tid < 48) {
      int c   = (tid & 1) ? 65 : 0;
      int cig = (tid >> 1) & 3;
      int r   = tid >> 3;          // 0..5
      int y_in = y0 - 1 + r;
      int x_in = x0 - 1 + c;
      bool inb = ((unsigned)y_in < 128u) & ((unsigned)x_in < 128u);
      unsigned int pk[4] = {0u, 0u, 0u, 0u};
      if (inb) {
        const float* src = xb + (size_t)(h * 32 + cig * 8) * (HH * WW) + y_in * WW + x_in;
        float v[8];
#pragma unroll
        for (int j = 0; j < 8; ++j) v[j] = src[(size_t)j * (HH * WW)];
#pragma unroll
        for (int w = 0; w < 4; ++w) pk[w] = pack2bf(v[2 * w], v[2 * w + 1]);
      }
      int byte = (r * 68 + c) * 64 + cig * 16;
      byte ^= ((c ^ (c >> 2)) & 3) << 4;
      *(uint4*)(sbuf + byte) = make_uint4(pk[0], pk[1], pk[2], pk[3]);
    }
  };

  auto compute_half = [&](int h) {
#pragma unroll
    for (int tap = 0; tap < 9; ++tap) {
      const int ky = tap / 3, kx = tap - ky * 3;
      const unsigned short* wbase = wfrag + (size_t)(h * 9 + tap) * 2048 + lane * 8;
      bf16x8 af[4];
#pragma unroll
      for (int cot = 0; cot < 4; ++cot)
        af[cot] = *(const bf16x8*)(wbase + cot * 512);
      bf16x8 pf[4];
      const int r = wv + ky;
#pragma unroll
      for (int m = 0; m < 4; ++m) {
        int c = m * 16 + pix + kx;
        int byte = (r * 68 + c) * 64 + g * 16;
        byte ^= ((c ^ (c >> 2)) & 3) << 4;
        pf[m] = *(const bf16x8*)(sbuf + byte);
      }
      __builtin_amdgcn_s_setprio(1);
#pragma unroll
      for (int cot = 0; cot < 4; ++cot)
#pragma unroll
        for (int m = 0; m < 4; ++m)
          acc[cot][m] = __builtin_amdgcn_mfma_f32_16x16x32_bf16(af[cot], pf[m],
                                                                acc[cot][m], 0, 0, 0);
      __builtin_amdgcn_s_setprio(0);
    }
  };

  stage_half(0);
  __syncthreads();
  compute_half(0);
  __syncthreads();
  stage_half(1);
  __syncthreads();
  compute_half(1);

  // ---- epilogue: add boundary-case table, coalesced nontemporal stores ----
  const int y  = y0 + wv;
  const int cy = (y == 0) ? 0 : ((y == HH - 1) ? 2 : 1);
  const float* extb = ext + (size_t)b * 64 * 9;
#pragma unroll
  for (int cot = 0; cot < 4; ++cot) {
#pragma unroll
    for (int m = 0; m < 4; ++m) {
      int xg = x0 + m * 16 + pix;
      int cx = (xg == 0) ? 0 : ((xg == WW - 1) ? 2 : 1);
#pragma unroll
      for (int j = 0; j < 4; ++j) {
        int co = cot * 16 + g * 4 + j;
        float v = acc[cot][m][j] + extb[co * 9 + cy * 3 + cx];
        __builtin_nontemporal_store(v, &out[(((size_t)b * 64 + co) * HH + y) * WW + xg]);
      }
    }
  }
}

extern "C" void kernel_launch(void* const* d_in, const int* in_sizes, int n_in,
                              void* d_out, int out_size, void* d_ws, size_t ws_size,
                              hipStream_t stream) {
  const float* x        = (const float*)d_in[0];
  const float* extra_in = (const float*)d_in[1];
  const float* conv_w   = (const float*)d_in[2];
  const float* conv_b   = (const float*)d_in[3];
  const float* extra_w  = (const float*)d_in[4];
  const float* extra_b  = (const float*)d_in[5];
  float* out = (float*)d_out;

  unsigned short* wfrag = (unsigned short*)d_ws;              // 73728 B
  float* ext = (float*)((char*)d_ws + 73728);                 // 73728 B

  hipLaunchKernelGGL(prep_wfrag, dim3(144), dim3(256), 0, stream, conv_w, wfrag);
  hipLaunchKernelGGL(prep_ext,   dim3(8),   dim3(256), 0, stream,
                     extra_in, extra_w, conv_b, extra_b, ext);
  hipLaunchKernelGGL(conv_mfma, dim3(2, 32, 32), dim3(256), 0, stream,
                     x, wfrag, ext, out);
}

// Round 7
// 107.970 us; speedup vs baseline: 1.2252x; 1.0126x over previous
//
#include <hip/hip_runtime.h>

#define HH 128
#define WW 128

typedef __bf16 bf16x8 __attribute__((ext_vector_type(8)));
typedef __bf16 bf16x2 __attribute__((ext_vector_type(2)));
typedef float f32x4 __attribute__((ext_vector_type(4)));

static __device__ __forceinline__ unsigned short f2bf(float f) {
  unsigned int u = __float_as_uint(f);
  u = (u + 0x7FFFu + ((u >> 16) & 1u)) >> 16;  // RNE
  return (unsigned short)u;
}

// hardware packed f32->bf16 (RNE), 2 elems -> one u32
static __device__ __forceinline__ unsigned int pack2bf(float lo, float hi) {
  bf16x2 v;
  v[0] = (__bf16)lo;
  v[1] = (__bf16)hi;
  return __builtin_bit_cast(unsigned int, v);
}

// ---------------------------------------------------------------------------
// Prep 1: pack conv_w [co][ci][tap] into MFMA A-fragment order (bf16):
//   wfrag[f = h*9+tap][cotile][lane][i] = conv_w[cotile*16 + lane%16]
//                                               [h*32 + (lane/16)*8 + i][tap]
// ---------------------------------------------------------------------------
__global__ __launch_bounds__(256) void prep_wfrag(const float* __restrict__ conv_w,
                                                  unsigned short* __restrict__ wfrag) {
  int tid = blockIdx.x * 256 + threadIdx.x;
  if (tid >= 18 * 2048) return;
  int i    = tid & 7;
  int lane = (tid >> 3) & 63;
  int cot  = (tid >> 9) & 3;
  int f    = tid >> 11;           // 0..17
  int h    = f / 9;               // ci half
  int tap  = f - h * 9;
  int co   = cot * 16 + (lane & 15);
  int ci   = h * 32 + (lane >> 4) * 8 + i;
  wfrag[tid] = f2bf(conv_w[(co * 64 + ci) * 9 + tap]);
}

// ---------------------------------------------------------------------------
// Prep 2: grouped conv of spatially-constant input -> 9-case boundary table
//   ext[b][co][cy][cx]  (includes conv_b + extra_b)
// ---------------------------------------------------------------------------
__global__ __launch_bounds__(256) void prep_ext(const float* __restrict__ extra_in,
                                                const float* __restrict__ extra_w,
                                                const float* __restrict__ conv_b,
                                                const float* __restrict__ extra_b,
                                                float* __restrict__ ext) {
  int t = blockIdx.x * 256 + threadIdx.x;
  if (t >= 32 * 64) return;
  int b = t >> 6, co = t & 63;
  float base = conv_b[co] + extra_b[co];
  float acc[3][3];
#pragma unroll
  for (int i = 0; i < 3; ++i)
#pragma unroll
    for (int j = 0; j < 3; ++j) acc[i][j] = 0.f;

#pragma unroll
  for (int f = 0; f < 3; ++f) {
    float e = extra_in[b * 192 + co * 3 + f];
    const float* w = extra_w + (co * 3 + f) * 9;
    float rs[3][3];
#pragma unroll
    for (int ky = 0; ky < 3; ++ky) {
      float w0 = w[ky * 3 + 0], w1 = w[ky * 3 + 1], w2 = w[ky * 3 + 2];
      rs[ky][0] = w1 + w2;
      rs[ky][1] = w0 + w1 + w2;
      rs[ky][2] = w0 + w1;
    }
#pragma unroll
    for (int cx = 0; cx < 3; ++cx) {
      acc[0][cx] += e * (rs[1][cx] + rs[2][cx]);
      acc[1][cx] += e * (rs[0][cx] + rs[1][cx] + rs[2][cx]);
      acc[2][cx] += e * (rs[0][cx] + rs[1][cx]);
    }
  }
#pragma unroll
  for (int cy = 0; cy < 3; ++cy)
#pragma unroll
    for (int cx = 0; cx < 3; ++cx)
      ext[t * 9 + cy * 3 + cx] = base + acc[cy][cx];
}

// ---------------------------------------------------------------------------
// Main: implicit-GEMM conv via mfma_f32_16x16x32_bf16 (r3 chassis).
// Block = (batch, 4 rows x 64 cols), 4 waves, wave = 1 output row.
// ci halves staged one at a time into LDS [6 r][68 c][32 ci] bf16 (25.5 KB).
// Staging: float2 interior pairs (guard-free 3x256 items) + scalar border;
// hardware v_cvt_pk bf16 conversion. Strict stage->sync->compute phases.
// Plain cached stores (nontemporal caused partial-line write amplification:
// WRITE_SIZE 131 -> 212 MB in r6 — L2 is what coalesces the 4x64B chunks).
// Swizzle: byte ^= ((c ^ (c>>2)) & 3) << 4  (2-way lane aliasing = free).
// ---------------------------------------------------------------------------
__global__ __launch_bounds__(256, 3) void conv_mfma(const float* __restrict__ x,
                                                    const unsigned short* __restrict__ wfrag,
                                                    const float* __restrict__ ext,
                                                    float* __restrict__ out) {
  const int b  = blockIdx.z;
  const int y0 = blockIdx.y * 4;
  const int x0 = blockIdx.x * 64;
  const int tid  = threadIdx.x;
  const int lane = tid & 63;
  const int wv   = tid >> 6;  // wave id = output row offset

  __shared__ __align__(16) unsigned char sbuf[6 * 68 * 64];  // [r][c][32ci] bf16

  const float* xb = x + (size_t)b * 64 * HH * WW;

  f32x4 acc[4][4];
#pragma unroll
  for (int i = 0; i < 4; ++i)
#pragma unroll
    for (int j = 0; j < 4; ++j) acc[i][j] = (f32x4){0.f, 0.f, 0.f, 0.f};

  const int pix = lane & 15;
  const int g   = lane >> 4;

  // ---- stage one ci-half (h) of the 6x66 halo into sbuf ----
  auto stage_half = [&](int h) {
    // interior: c pairs (1+2cp, 2+2cp), cp 0..31; 32*4*6 = 768 = 3*256 items
#pragma unroll
    for (int it = 0; it < 3; ++it) {
      int q   = tid + it * 256;
      int cp  = q & 31;
      int cig = (q >> 5) & 3;
      int r   = q >> 7;            // 0..5
      int c   = 1 + 2 * cp;
      int y_in = y0 - 1 + r;
      int x_in = x0 + 2 * cp;      // = x0 - 1 + c, even -> 8B aligned
      unsigned int pkA[4] = {0u, 0u, 0u, 0u};
      unsigned int pkB[4] = {0u, 0u, 0u, 0u};
      if ((unsigned)y_in < 128u) {
        const float* src = xb + (size_t)(h * 32 + cig * 8) * (HH * WW) + y_in * WW + x_in;
        float2 f[8];
#pragma unroll
        for (int j = 0; j < 8; ++j) f[j] = *(const float2*)(src + (size_t)j * (HH * WW));
#pragma unroll
        for (int w = 0; w < 4; ++w) {
          pkA[w] = pack2bf(f[2 * w].x, f[2 * w + 1].x);
          pkB[w] = pack2bf(f[2 * w].y, f[2 * w + 1].y);
        }
      }
      int baseA = (r * 68 + c) * 64 + cig * 16;
      int baseB = (r * 68 + c + 1) * 64 + cig * 16;
      baseA ^= ((c ^ (c >> 2)) & 3) << 4;
      baseB ^= (((c + 1) ^ ((c + 1) >> 2)) & 3) << 4;
      *(uint4*)(sbuf + baseA) = make_uint4(pkA[0], pkA[1], pkA[2], pkA[3]);
      *(uint4*)(sbuf + baseB) = make_uint4(pkB[0], pkB[1], pkB[2], pkB[3]);
    }
    // border: c in {0, 65}; 2*4*6 = 48 items
    if (tid < 48) {
      int c   = (tid & 1) ? 65 : 0;
      int cig = (tid >> 1) & 3;
      int r   = tid >> 3;          // 0..5
      int y_in = y0 - 1 + r;
      int x_in = x0 - 1 + c;
      bool inb = ((unsigned)y_in < 128u) & ((unsigned)x_in < 128u);
      unsigned int pk[4] = {0u, 0u, 0u, 0u};
      if (inb) {
        const float* src = xb + (size_t)(h * 32 + cig * 8) * (HH * WW) + y_in * WW + x_in;
        float v[8];
#pragma unroll
        for (int j = 0; j < 8; ++j) v[j] = src[(size_t)j * (HH * WW)];
#pragma unroll
        for (int w = 0; w < 4; ++w) pk[w] = pack2bf(v[2 * w], v[2 * w + 1]);
      }
      int byte = (r * 68 + c) * 64 + cig * 16;
      byte ^= ((c ^ (c >> 2)) & 3) << 4;
      *(uint4*)(sbuf + byte) = make_uint4(pk[0], pk[1], pk[2], pk[3]);
    }
  };

  auto compute_half = [&](int h) {
#pragma unroll
    for (int tap = 0; tap < 9; ++tap) {
      const int ky = tap / 3, kx = tap - ky * 3;
      const unsigned short* wbase = wfrag + (size_t)(h * 9 + tap) * 2048 + lane * 8;
      bf16x8 af[4];
#pragma unroll
      for (int cot = 0; cot < 4; ++cot)
        af[cot] = *(const bf16x8*)(wbase + cot * 512);
      bf16x8 pf[4];
      const int r = wv + ky;
#pragma unroll
      for (int m = 0; m < 4; ++m) {
        int c = m * 16 + pix + kx;
        int byte = (r * 68 + c) * 64 + g * 16;
        byte ^= ((c ^ (c >> 2)) & 3) << 4;
        pf[m] = *(const bf16x8*)(sbuf + byte);
      }
      __builtin_amdgcn_s_setprio(1);
#pragma unroll
      for (int cot = 0; cot < 4; ++cot)
#pragma unroll
        for (int m = 0; m < 4; ++m)
          acc[cot][m] = __builtin_amdgcn_mfma_f32_16x16x32_bf16(af[cot], pf[m],
                                                                acc[cot][m], 0, 0, 0);
      __builtin_amdgcn_s_setprio(0);
    }
  };

  stage_half(0);
  __syncthreads();
  compute_half(0);
  __syncthreads();
  stage_half(1);
  __syncthreads();
  compute_half(1);

  // ---- epilogue: add boundary-case table, coalesced cached stores ----
  const int y  = y0 + wv;
  const int cy = (y == 0) ? 0 : ((y == HH - 1) ? 2 : 1);
  const float* extb = ext + (size_t)b * 64 * 9;
#pragma unroll
  for (int cot = 0; cot < 4; ++cot) {
#pragma unroll
    for (int m = 0; m < 4; ++m) {
      int xg = x0 + m * 16 + pix;
      int cx = (xg == 0) ? 0 : ((xg == WW - 1) ? 2 : 1);
#pragma unroll
      for (int j = 0; j < 4; ++j) {
        int co = cot * 16 + g * 4 + j;
        float v = acc[cot][m][j] + extb[co * 9 + cy * 3 + cx];
        out[(((size_t)b * 64 + co) * HH + y) * WW + xg] = v;
      }
    }
  }
}

extern "C" void kernel_launch(void* const* d_in, const int* in_sizes, int n_in,
                              void* d_out, int out_size, void* d_ws, size_t ws_size,
                              hipStream_t stream) {
  const float* x        = (const float*)d_in[0];
  const float* extra_in = (const float*)d_in[1];
  const float* conv_w   = (const float*)d_in[2];
  const float* conv_b   = (const float*)d_in[3];
  const float* extra_w  = (const float*)d_in[4];
  const float* extra_b  = (const float*)d_in[5];
  float* out = (float*)d_out;

  unsigned short* wfrag = (unsigned short*)d_ws;              // 73728 B
  float* ext = (float*)((char*)d_ws + 73728);                 // 73728 B

  hipLaunchKernelGGL(prep_wfrag, dim3(144), dim3(256), 0, stream, conv_w, wfrag);
  hipLaunchKernelGGL(prep_ext,   dim3(8),   dim3(256), 0, stream,
                     extra_in, extra_w, conv_b, extra_b, ext);
  hipLaunchKernelGGL(conv_mfma, dim3(2, 32, 32), dim3(256), 0, stream,
                     x, wfrag, ext, out);
}

// Round 8
// 90.096 us; speedup vs baseline: 1.4682x; 1.1984x over previous
//
#include <hip/hip_runtime.h>

#define HH 128
#define WW 128
#define LDS_W 26112  // wbuf offset (sbuf occupies [0, 26112))

typedef __bf16 bf16x8 __attribute__((ext_vector_type(8)));
typedef __bf16 bf16x2 __attribute__((ext_vector_type(2)));
typedef float f32x4 __attribute__((ext_vector_type(4)));

static __device__ __forceinline__ unsigned short f2bf(float f) {
  unsigned int u = __float_as_uint(f);
  u = (u + 0x7FFFu + ((u >> 16) & 1u)) >> 16;  // RNE
  return (unsigned short)u;
}

// hardware packed f32->bf16 (RNE), 2 elems -> one u32
static __device__ __forceinline__ unsigned int pack2bf(float lo, float hi) {
  bf16x2 v;
  v[0] = (__bf16)lo;
  v[1] = (__bf16)hi;
  return __builtin_bit_cast(unsigned int, v);
}

// ---------------------------------------------------------------------------
// Prep 1: pack conv_w [co][ci][tap] into MFMA A-fragment order (bf16):
//   wfrag[f = h*9+tap][cotile][lane][i] = conv_w[cotile*16 + lane%16]
//                                               [h*32 + (lane/16)*8 + i][tap]
// ---------------------------------------------------------------------------
__global__ __launch_bounds__(256) void prep_wfrag(const float* __restrict__ conv_w,
                                                  unsigned short* __restrict__ wfrag) {
  int tid = blockIdx.x * 256 + threadIdx.x;
  if (tid >= 18 * 2048) return;
  int i    = tid & 7;
  int lane = (tid >> 3) & 63;
  int cot  = (tid >> 9) & 3;
  int f    = tid >> 11;           // 0..17
  int h    = f / 9;               // ci half
  int tap  = f - h * 9;
  int co   = cot * 16 + (lane & 15);
  int ci   = h * 32 + (lane >> 4) * 8 + i;
  wfrag[tid] = f2bf(conv_w[(co * 64 + ci) * 9 + tap]);
}

// ---------------------------------------------------------------------------
// Prep 2: grouped conv of spatially-constant input -> 9-case boundary table
//   ext[b][co][cy][cx]  (includes conv_b + extra_b)
// ---------------------------------------------------------------------------
__global__ __launch_bounds__(256) void prep_ext(const float* __restrict__ extra_in,
                                                const float* __restrict__ extra_w,
                                                const float* __restrict__ conv_b,
                                                const float* __restrict__ extra_b,
                                                float* __restrict__ ext) {
  int t = blockIdx.x * 256 + threadIdx.x;
  if (t >= 32 * 64) return;
  int b = t >> 6, co = t & 63;
  float base = conv_b[co] + extra_b[co];
  float acc[3][3];
#pragma unroll
  for (int i = 0; i < 3; ++i)
#pragma unroll
    for (int j = 0; j < 3; ++j) acc[i][j] = 0.f;

#pragma unroll
  for (int f = 0; f < 3; ++f) {
    float e = extra_in[b * 192 + co * 3 + f];
    const float* w = extra_w + (co * 3 + f) * 9;
    float rs[3][3];
#pragma unroll
    for (int ky = 0; ky < 3; ++ky) {
      float w0 = w[ky * 3 + 0], w1 = w[ky * 3 + 1], w2 = w[ky * 3 + 2];
      rs[ky][0] = w1 + w2;
      rs[ky][1] = w0 + w1 + w2;
      rs[ky][2] = w0 + w1;
    }
#pragma unroll
    for (int cx = 0; cx < 3; ++cx) {
      acc[0][cx] += e * (rs[1][cx] + rs[2][cx]);
      acc[1][cx] += e * (rs[0][cx] + rs[1][cx] + rs[2][cx]);
      acc[2][cx] += e * (rs[0][cx] + rs[1][cx]);
    }
  }
#pragma unroll
  for (int cy = 0; cy < 3; ++cy)
#pragma unroll
    for (int cx = 0; cx < 3; ++cx)
      ext[t * 9 + cy * 3 + cx] = base + acc[cy][cx];
}

// ---------------------------------------------------------------------------
// Main: implicit-GEMM conv via mfma_f32_16x16x32_bf16.
// Block = (batch, 4 rows x 64 cols), 4 waves, wave = 1 output row.
// BOTH operands in LDS:
//   sbuf [6 r][68 c][32 ci] bf16 (25.5 KB), float2+cvt_pk staging (r7 path);
//   wbuf = per-ci-half wfrag slice (36 KB) DMA'd via global_load_lds (16B).
// Compute reads af/pf via ds_read_b128 only -> no vmcnt in the MFMA path.
// Epilogue: 2 x 32KB LDS-transpose chunks -> dwordx4 stores covering FULL
// aligned 256B lines (fixes the r5-r7 partial-line WRITE amplification).
// ---------------------------------------------------------------------------
__global__ __launch_bounds__(256, 3) void conv_mfma(const float* __restrict__ x,
                                                    const unsigned short* __restrict__ wfrag,
                                                    const float* __restrict__ ext,
                                                    float* __restrict__ out) {
  const int b  = blockIdx.z;
  const int y0 = blockIdx.y * 4;
  const int x0 = blockIdx.x * 64;
  const int tid  = threadIdx.x;
  const int lane = tid & 63;
  const int wv   = tid >> 6;  // wave id = output row offset

  __shared__ __align__(16) unsigned char lds[LDS_W + 36864];  // 62976 B

  const float* xb = x + (size_t)b * 64 * HH * WW;

  f32x4 acc[4][4];
#pragma unroll
  for (int i = 0; i < 4; ++i)
#pragma unroll
    for (int j = 0; j < 4; ++j) acc[i][j] = (f32x4){0.f, 0.f, 0.f, 0.f};

  const int pix = lane & 15;
  const int g   = lane >> 4;

  // ---- DMA one ci-half of wfrag (36864 B, layout-identical) into wbuf ----
  auto wload_half = [&](int h) {
    const char* wsrc = (const char*)(wfrag + (size_t)h * 9 * 2048);
#pragma unroll
    for (int it = 0; it < 9; ++it) {
      int off = (tid + it * 256) * 16;
      __builtin_amdgcn_global_load_lds(
          (const __attribute__((address_space(1))) unsigned int*)(wsrc + off),
          (__attribute__((address_space(3))) unsigned int*)(lds + LDS_W + off),
          16, 0, 0);
    }
  };

  // ---- stage one ci-half (h) of the 6x66 halo into sbuf ----
  auto stage_half = [&](int h) {
    // interior: c pairs (1+2cp, 2+2cp), cp 0..31; 32*4*6 = 768 = 3*256 items
#pragma unroll
    for (int it = 0; it < 3; ++it) {
      int q   = tid + it * 256;
      int cp  = q & 31;
      int cig = (q >> 5) & 3;
      int r   = q >> 7;            // 0..5
      int c   = 1 + 2 * cp;
      int y_in = y0 - 1 + r;
      int x_in = x0 + 2 * cp;      // = x0 - 1 + c, even -> 8B aligned
      unsigned int pkA[4] = {0u, 0u, 0u, 0u};
      unsigned int pkB[4] = {0u, 0u, 0u, 0u};
      if ((unsigned)y_in < 128u) {
        const float* src = xb + (size_t)(h * 32 + cig * 8) * (HH * WW) + y_in * WW + x_in;
        float2 f[8];
#pragma unroll
        for (int j = 0; j < 8; ++j) f[j] = *(const float2*)(src + (size_t)j * (HH * WW));
#pragma unroll
        for (int w = 0; w < 4; ++w) {
          pkA[w] = pack2bf(f[2 * w].x, f[2 * w + 1].x);
          pkB[w] = pack2bf(f[2 * w].y, f[2 * w + 1].y);
        }
      }
      int baseA = (r * 68 + c) * 64 + cig * 16;
      int baseB = (r * 68 + c + 1) * 64 + cig * 16;
      baseA ^= ((c ^ (c >> 2)) & 3) << 4;
      baseB ^= (((c + 1) ^ ((c + 1) >> 2)) & 3) << 4;
      *(uint4*)(lds + baseA) = make_uint4(pkA[0], pkA[1], pkA[2], pkA[3]);
      *(uint4*)(lds + baseB) = make_uint4(pkB[0], pkB[1], pkB[2], pkB[3]);
    }
    // border: c in {0, 65}; 2*4*6 = 48 items
    if (tid < 48) {
      int c   = (tid & 1) ? 65 : 0;
      int cig = (tid >> 1) & 3;
      int r   = tid >> 3;          // 0..5
      int y_in = y0 - 1 + r;
      int x_in = x0 - 1 + c;
      bool inb = ((unsigned)y_in < 128u) & ((unsigned)x_in < 128u);
      unsigned int pk[4] = {0u, 0u, 0u, 0u};
      if (inb) {
        const float* src = xb + (size_t)(h * 32 + cig * 8) * (HH * WW) + y_in * WW + x_in;
        float v[8];
#pragma unroll
        for (int j = 0; j < 8; ++j) v[j] = src[(size_t)j * (HH * WW)];
#pragma unroll
        for (int w = 0; w < 4; ++w) pk[w] = pack2bf(v[2 * w], v[2 * w + 1]);
      }
      int byte = (r * 68 + c) * 64 + cig * 16;
      byte ^= ((c ^ (c >> 2)) & 3) << 4;
      *(uint4*)(lds + byte) = make_uint4(pk[0], pk[1], pk[2], pk[3]);
    }
  };

  // ---- compute current half from sbuf + wbuf (LDS only, no vmcnt path) ----
  auto compute_half = [&]() {
#pragma unroll
    for (int tap = 0; tap < 9; ++tap) {
      const int ky = tap / 3, kx = tap - ky * 3;
      bf16x8 af[4];
#pragma unroll
      for (int cot = 0; cot < 4; ++cot)
        af[cot] = *(const bf16x8*)(lds + LDS_W + tap * 4096 + cot * 1024 + lane * 16);
      bf16x8 pf[4];
      const int r = wv + ky;
#pragma unroll
      for (int m = 0; m < 4; ++m) {
        int c = m * 16 + pix + kx;
        int byte = (r * 68 + c) * 64 + g * 16;
        byte ^= ((c ^ (c >> 2)) & 3) << 4;
        pf[m] = *(const bf16x8*)(lds + byte);
      }
#pragma unroll
      for (int cot = 0; cot < 4; ++cot)
#pragma unroll
        for (int m = 0; m < 4; ++m)
          acc[cot][m] = __builtin_amdgcn_mfma_f32_16x16x32_bf16(af[cot], pf[m],
                                                                acc[cot][m], 0, 0, 0);
    }
  };

  wload_half(0);
  stage_half(0);
  __syncthreads();
  compute_half();
  __syncthreads();
  wload_half(1);
  stage_half(1);
  __syncthreads();
  compute_half();
  __syncthreads();

  // ---- epilogue: 2 x 32KB LDS-transpose chunks -> full-line stores ----
  // chunk LDS layout: addr = col2*1024 + wv*256 + x*4, swizzle ^((col2>>2)&1)<<6
  const int y  = y0 + wv;
  const int cy = (y == 0) ? 0 : ((y == HH - 1) ? 2 : 1);
  const float* extb = ext + (size_t)b * 64 * 9;
#pragma unroll
  for (int cc = 0; cc < 2; ++cc) {
#pragma unroll
    for (int cot2 = 0; cot2 < 2; ++cot2) {
      const int cot = cc * 2 + cot2;
#pragma unroll
      for (int m = 0; m < 4; ++m) {
        int xg = x0 + m * 16 + pix;
        int cx = (xg == 0) ? 0 : ((xg == WW - 1) ? 2 : 1);
#pragma unroll
        for (int j = 0; j < 4; ++j) {
          int col2 = cot2 * 16 + g * 4 + j;
          int co   = cc * 32 + col2;
          float v = acc[cot][m][j] + extb[co * 9 + cy * 3 + cx];
          int byte = (col2 * 1024 + wv * 256 + (m * 16 + pix) * 4) ^ (((col2 >> 2) & 1) << 6);
          *(float*)(lds + byte) = v;
        }
      }
    }
    __syncthreads();
#pragma unroll
    for (int p = 0; p < 8; ++p) {
      int idx  = p * 256 + tid;
      int col2 = idx >> 6;
      int wv2  = (idx >> 4) & 3;
      int xq   = idx & 15;
      int byte = (col2 * 1024 + wv2 * 256 + xq * 16) ^ (((col2 >> 2) & 1) << 6);
      f32x4 v = *(const f32x4*)(lds + byte);
      int co = cc * 32 + col2;
      *(f32x4*)&out[(((size_t)b * 64 + co) * HH + (y0 + wv2)) * WW + x0 + xq * 4] = v;
    }
    if (cc == 0) __syncthreads();
  }
}

extern "C" void kernel_launch(void* const* d_in, const int* in_sizes, int n_in,
                              void* d_out, int out_size, void* d_ws, size_t ws_size,
                              hipStream_t stream) {
  const float* x        = (const float*)d_in[0];
  const float* extra_in = (const float*)d_in[1];
  const float* conv_w   = (const float*)d_in[2];
  const float* conv_b   = (const float*)d_in[3];
  const float* extra_w  = (const float*)d_in[4];
  const float* extra_b  = (const float*)d_in[5];
  float* out = (float*)d_out;

  unsigned short* wfrag = (unsigned short*)d_ws;              // 73728 B
  float* ext = (float*)((char*)d_ws + 73728);                 // 73728 B

  hipLaunchKernelGGL(prep_wfrag, dim3(144), dim3(256), 0, stream, conv_w, wfrag);
  hipLaunchKernelGGL(prep_ext,   dim3(8),   dim3(256), 0, stream,
                     extra_in, extra_w, conv_b, extra_b, ext);
  hipLaunchKernelGGL(conv_mfma, dim3(2, 32, 32), dim3(256), 0, stream,
                     x, wfrag, ext, out);
}